// Round 7
// baseline (363.182 us; speedup 1.0000x reference)
//
#include <hip/hip_runtime.h>

// ---------- types ----------
typedef __attribute__((ext_vector_type(8))) short bf16x8;   // 8 bf16 in 4 VGPRs
typedef __attribute__((ext_vector_type(4))) short bf16x4;   // 4 bf16 in 2 VGPRs
typedef __attribute__((ext_vector_type(4))) float f32x4;    // MFMA C/D

#define MFMA32(a,b,c) __builtin_amdgcn_mfma_f32_16x16x32_bf16((a),(b),(c),0,0,0)
#define MFMA16(a,b,c) __builtin_amdgcn_mfma_f32_16x16x16bf16_1k((a),(b),(c),0,0,0)
#define LOG2E 1.44269504f

__device__ __forceinline__ unsigned short f2bf(float f) {
  unsigned int u = __float_as_uint(f);
  u += 0x7fffu + ((u >> 16) & 1u);      // round-to-nearest-even
  return (unsigned short)(u >> 16);
}

// async global->LDS, 16B per lane; LDS dest = wave-uniform base + lane*16
__device__ __forceinline__ void cp16(const void* g, void* l) {
  __builtin_amdgcn_global_load_lds((const __attribute__((address_space(1))) void*)g,
                                   (__attribute__((address_space(3))) void*)l, 16, 0, 0);
}

// ---------- fp32 -> bf16 (query, memory) + bias pre-transform, one launch ----
__global__ void conv_both(const float* __restrict__ q, const float* __restrict__ m,
                          const float* __restrict__ bias,
                          unsigned short* __restrict__ qo, unsigned short* __restrict__ mo,
                          float* __restrict__ bz) {
  int i = blockIdx.x * 256 + threadIdx.x;   // grid covers 4718592 + 4096 float4s
  if (i < 524288) {
    float4 v = ((const float4*)q)[i];
    ushort4 o; o.x = f2bf(v.x); o.y = f2bf(v.y); o.z = f2bf(v.z); o.w = f2bf(v.w);
    ((ushort4*)qo)[i] = o;
  } else if (i < 4718592) {
    int j = i - 524288;
    float4 v = ((const float4*)m)[j];
    ushort4 o; o.x = f2bf(v.x); o.y = f2bf(v.y); o.z = f2bf(v.z); o.w = f2bf(v.w);
    ((ushort4*)mo)[j] = o;
  } else {
    int j = i - 4718592;                   // < 4096: bias -> bias*log2e - 16
    float4 v = ((const float4*)bias)[j];
    float4 o;
    o.x = __builtin_fmaf(v.x, LOG2E, -16.f);
    o.y = __builtin_fmaf(v.y, LOG2E, -16.f);
    o.z = __builtin_fmaf(v.z, LOG2E, -16.f);
    o.w = __builtin_fmaf(v.w, LOG2E, -16.f);
    ((float4*)bz)[j] = o;
  }
}

// ---------- 1024x1024 transpose+convert for all 4 weights in one launch ----------
__global__ void transpose4(const float* __restrict__ Wq, const float* __restrict__ Wk,
                           const float* __restrict__ Wv, const float* __restrict__ Wo,
                           unsigned short* __restrict__ dst) {
  __shared__ float t[32][33];
  int z = blockIdx.z;
  const float* W = (z == 0) ? Wq : (z == 1) ? Wk : (z == 2) ? Wv : Wo;
  unsigned short* WT = dst + (size_t)z * 1048576;
  int bx = blockIdx.x * 32, by = blockIdx.y * 32;
  int x = threadIdx.x, y0 = threadIdx.y;
#pragma unroll
  for (int r = 0; r < 4; ++r)
    t[y0 + r * 8][x] = W[(size_t)(by + y0 + r * 8) * 1024 + bx + x];
  __syncthreads();
#pragma unroll
  for (int r = 0; r < 4; ++r)
    WT[(size_t)(bx + y0 + r * 8) * 1024 + by + x] = f2bf(t[x][y0 + r * 8]);
}

// ---------- fused K/V projection — r12: B-from-L2 + A quad-buffer -----------
// r11 post-mortem: per tile LDS reads 2304 cyc + MFMA 2483 cyc measured fully
// SERIAL (5250 cyc/tile) across 3 schedule variants — barrier-locked waves all
// get LDS data at the same time, so the two pipes alternate. Fix attacks the
// operand sources:
//  * B (Wk/Wv) fragments read DIRECTLY from global (L1/L2-resident: 32KB/step
//    per block, same-XCD blocks share the panel). B leaves the LDS pipe AND
//    the barrier protocol entirely; its latency rides the vmem pipe under the
//    MFMA clusters.
//  * A alone staged in LDS -> 32KB/tile -> QUAD buffer (128KB), sync once per
//    2-tile window (8 syncs total). Stages land a full window (~5000 cyc)
//    ahead -> HBM latency hidden. LDS reads drop 24->8 per wave per tile.
// Window s (0..7): __syncthreads; stage A(2s+2),A(2s+3) -> bufs (..)&3;
//   for tt in {2s,2s+1}: 8 LDS A-reads + 32 global B-loads + 64 MFMA.
// Hazards: reads of bufs {2s,2s+1} drained by lgkmcnt(0) at sync(s+1) before
// window s+1 restages them; stages drained by vmcnt(0) at sync(s+1) before
// their reads. T2 swizzle on A retained; T5 setprio retained.
__global__ __launch_bounds__(512, 2) void gemm_kv(
    const unsigned short* __restrict__ A,   // mbf [16384][1024]
    const unsigned short* __restrict__ Bk,  // WkT [1024][1024]
    const unsigned short* __restrict__ Bv,  // WvT [1024][1024]
    unsigned short* __restrict__ Kp,        // [16384][1024]
    unsigned short* __restrict__ Vt)        // [1024][16384]
{
  // 4 A-buffers: buf b at b*16384 ushorts = A[256 rows][64 k] (32 KB each)
  __shared__ __attribute__((aligned(16))) unsigned short lds[65536]; // 128 KB
  const int tid = threadIdx.x;
  const int w = tid >> 6, lane = tid & 63;
  const int lh = lane & 15, q4 = lane >> 4;
  const int id = blockIdx.x;
  const int xcd = id & 7, j = id >> 3;
  const int tm = (xcd * 8 + (j >> 3)) * 256;  // 8 m-strips per XCD, n inner
  const int tn = (j & 7) * 128;
  const int wm = (w >> 1) * 64, wn = (w & 1) * 64;

  // A staging lane geometry (source-side T2 swizzle, 64B row segments whole)
  const int r8 = lane >> 3;                       // row within 8-row chunk
  const int scol = ((lane & 7) ^ r8) * 8;         // swizzled source k-slot
  const int srow = w * 8 + r8;                    // row within 64-row chunk
  // fragment-read swizzled slot offsets (row&7 == lh&7 for all frag rows)
  const int fs0 = ((0 + q4) ^ (lh & 7)) * 8;
  const int fs1 = ((4 + q4) ^ (lh & 7)) * 8;

  const unsigned short* Ag = A + (size_t)tm * 1024 + scol;
  // B fragment bases: lane (lh,q4) reads row (tn+wn+n*16+lh), k-slot q4*8
  const unsigned short* Kg = Bk + (size_t)(tn + wn + lh) * 1024 + q4 * 8;
  const unsigned short* Vg = Bv + (size_t)(tn + wn + lh) * 1024 + q4 * 8;

#define STG_A(BUF,KT) do {                                                    \
    cp16(Ag + (size_t)(  0 + srow) * 1024 + (KT)*64, lds + (BUF)*16384 +    w*512); \
    cp16(Ag + (size_t)( 64 + srow) * 1024 + (KT)*64, lds + (BUF)*16384 + 4096 + w*512); \
    cp16(Ag + (size_t)(128 + srow) * 1024 + (KT)*64, lds + (BUF)*16384 + 8192 + w*512); \
    cp16(Ag + (size_t)(192 + srow) * 1024 + (KT)*64, lds + (BUF)*16384 + 12288 + w*512); \
  } while (0)

  f32x4 acck[4][4] = {}, accv[4][4] = {};

  // ---- prologue: stage tiles 0,1 into bufs 0,1 (drained by first sync)
  STG_A(0, 0);
  STG_A(1, 1);

  for (int s = 0; s < 8; ++s) {
    __syncthreads();                 // vmcnt(0)+lgkmcnt(0)+s_barrier
    if (s < 7) {
      STG_A((2 * s + 2) & 3, 2 * s + 2);
      STG_A((2 * s + 3) & 3, 2 * s + 3);
    }
#pragma unroll
    for (int u = 0; u < 2; ++u) {
      const int tt = 2 * s + u;
      const unsigned short* bse = lds + (tt & 3) * 16384;
      const int ko = tt * 64;
      // kh = 0
      {
        bf16x8 a0[4], bk0[4], bv0[4];
#pragma unroll
        for (int m = 0; m < 4; ++m)
          a0[m] = *(const bf16x8*)(bse + (wm + m * 16 + lh) * 64 + fs0);
#pragma unroll
        for (int n = 0; n < 4; ++n) {
          bk0[n] = *(const bf16x8*)(Kg + (size_t)(n * 16) * 1024 + ko);
          bv0[n] = *(const bf16x8*)(Vg + (size_t)(n * 16) * 1024 + ko);
        }
        __builtin_amdgcn_s_setprio(1);
#pragma unroll
        for (int m = 0; m < 4; ++m)
#pragma unroll
          for (int n = 0; n < 4; ++n) {
            acck[m][n] = MFMA32(a0[m], bk0[n], acck[m][n]);
            accv[m][n] = MFMA32(a0[m], bv0[n], accv[m][n]);
          }
        __builtin_amdgcn_s_setprio(0);
      }
      // kh = 1
      {
        bf16x8 a1[4], bk1[4], bv1[4];
#pragma unroll
        for (int m = 0; m < 4; ++m)
          a1[m] = *(const bf16x8*)(bse + (wm + m * 16 + lh) * 64 + fs1);
#pragma unroll
        for (int n = 0; n < 4; ++n) {
          bk1[n] = *(const bf16x8*)(Kg + (size_t)(n * 16) * 1024 + ko + 32);
          bv1[n] = *(const bf16x8*)(Vg + (size_t)(n * 16) * 1024 + ko + 32);
        }
        __builtin_amdgcn_s_setprio(1);
#pragma unroll
        for (int m = 0; m < 4; ++m)
#pragma unroll
          for (int n = 0; n < 4; ++n) {
            acck[m][n] = MFMA32(a1[m], bk1[n], acck[m][n]);
            accv[m][n] = MFMA32(a1[m], bv1[n], accv[m][n]);
          }
        __builtin_amdgcn_s_setprio(0);
      }
    }
  }

#undef STG_A

  // Kp epilogue: row-major 2B stores coalesce within lh groups (r4-verified)
#pragma unroll
  for (int m = 0; m < 4; ++m)
#pragma unroll
    for (int n = 0; n < 4; ++n) {
      int row = tm + wm + m * 16 + q4 * 4;
      int col = tn + wn + n * 16 + lh;
#pragma unroll
      for (int e = 0; e < 4; ++e)
        Kp[(size_t)(row + e) * 1024 + col] = f2bf(acck[m][n][e]);
    }

  // Vt epilogue via LDS: write C-layout (xor-swizzled 256-row tile), read back
  // coalesced (2-way write aliasing = free; readback 512B-contiguous per col).
  __syncthreads();
#pragma unroll
  for (int m = 0; m < 4; ++m)
#pragma unroll
    for (int n = 0; n < 4; ++n) {
      int row = wm + m * 16 + q4 * 4;       // block-local token (+e consecutive)
      int col = wn + n * 16 + lh;           // block-local d
      ushort4 v4;
      v4.x = f2bf(accv[m][n][0]); v4.y = f2bf(accv[m][n][1]);
      v4.z = f2bf(accv[m][n][2]); v4.w = f2bf(accv[m][n][3]);
      *(ushort4*)(lds + col * 256 + (row ^ ((col & 31) << 3))) = v4;
    }
  __syncthreads();
#pragma unroll
  for (int p = 0; p < 8; ++p) {
    int col = p * 16 + (tid >> 5);                  // 0..127
    int jb = tid & 31;                              // 8-ushort block in 256 rows
    const unsigned short* src = lds + col * 256 + ((jb ^ (col & 31)) << 3);
    *(int4*)(Vt + (size_t)(tn + col) * 16384 + tm + jb * 8) = *(const int4*)src;
  }
}

// ---------- bf16 GEMM 128x64 tile (q-proj, out-proj) ----------
// r12: quad-buffer, sync per 2 k-steps (1 wave/SIMD here — window pipelining
// hides the HBM stage latency that serialized each step). r6 T2 swizzle.
__global__ __launch_bounds__(256) void gemm_bt64(
    const unsigned short* __restrict__ A, const unsigned short* __restrict__ B,
    float* __restrict__ Cf, unsigned short* __restrict__ Cb,
    int M, int N, int K, float scale)
{
  // buffer b at b*6144 ushorts: A[128][32]@0, B[64][32]@4096
  __shared__ __attribute__((aligned(16))) unsigned short lds[24576]; // 48 KB
  int w = threadIdx.x >> 6, lane = threadIdx.x & 63;
  int lh = lane & 15, q4 = lane >> 4;
  int tm = blockIdx.y * 128, tn = blockIdx.x * 64;
  int wm = (w & 1) * 64, wn = (w >> 1) * 32;

  int srow = lane >> 2;
  int scol = ((lane & 3) ^ ((lane >> 3) & 3)) << 3;
  int q4s = (q4 ^ ((lh >> 1) & 3)) << 3;

#define STG64(BUF,K0)                                                          \
  {                                                                            \
    _Pragma("unroll") for (int i = 0; i < 2; ++i) {                            \
      int c = w * 2 + i;                                                       \
      cp16(A + (size_t)(tm + c * 16 + srow) * K + (K0) + scol,                 \
           lds + (BUF) * 6144 + c * 512);                                      \
    }                                                                          \
    cp16(B + (size_t)(tn + w * 16 + srow) * K + (K0) + scol,                   \
         lds + (BUF) * 6144 + 4096 + w * 512);                                 \
  }

  f32x4 acc[4][2] = {};
  const int nw = K >> 6;               // windows of 2 k-steps

  STG64(0, 0);
  STG64(1, 32);

  for (int s = 0; s < nw; ++s) {
    __syncthreads();                   // vmcnt(0)+lgkmcnt(0)+s_barrier
    if (s + 1 < nw) {
      STG64((2 * s + 2) & 3, (2 * s + 2) << 5);
      STG64((2 * s + 3) & 3, (2 * s + 3) << 5);
    }
#pragma unroll
    for (int u = 0; u < 2; ++u) {
      const unsigned short* bse = lds + ((2 * s + u) & 3) * 6144;
      bf16x8 afr[4], bfr[2];
#pragma unroll
      for (int r = 0; r < 4; ++r)
        afr[r] = *(const bf16x8*)(bse + (wm + r * 16 + lh) * 32 + q4s);
#pragma unroll
      for (int c = 0; c < 2; ++c)
        bfr[c] = *(const bf16x8*)(bse + 4096 + (wn + c * 16 + lh) * 32 + q4s);
      __builtin_amdgcn_s_setprio(1);
#pragma unroll
      for (int r = 0; r < 4; ++r)
#pragma unroll
        for (int c = 0; c < 2; ++c)
          acc[r][c] = MFMA32(afr[r], bfr[c], acc[r][c]);
      __builtin_amdgcn_s_setprio(0);
    }
  }
#undef STG64

#pragma unroll
  for (int r = 0; r < 4; ++r)
#pragma unroll
    for (int c = 0; c < 2; ++c)
#pragma unroll
      for (int e = 0; e < 4; ++e) {
        int row = tm + wm + r * 16 + q4 * 4 + e;
        int col = tn + wn + c * 16 + lh;
        if (Cb) Cb[(size_t)row * N + col] = f2bf(acc[r][c][e] * scale);
        else    Cf[(size_t)row * N + col] = acc[r][c][e] * scale;
      }
}

// ---------- attention v4 (round-5 proven): LDS-staged K/V, register P -------
__global__ __launch_bounds__(256) void attn_kernel(
    const unsigned short* __restrict__ Q, const unsigned short* __restrict__ Kp,
    const unsigned short* __restrict__ VT, const float* __restrict__ bz,
    float* __restrict__ po, float* __restrict__ lp)
{
  __shared__ __attribute__((aligned(16))) unsigned short Klds[4096]; // [64 tok][8 blk of 8]
  __shared__ __attribute__((aligned(16))) unsigned short Vlds[4096]; // [64 d][8 blk of 8]
  int w = threadIdx.x >> 6, lane = threadIdx.x & 63;
  int lh = lane & 15, q4 = lane >> 4;

  // XCD swizzle: same-bh blocks land on same XCD (bh & 7 == xcd)
  int id = blockIdx.x;
  int xcd = id & 7, j = id >> 3;
  int ql = j & 7;                   // 8 blocks per bh
  int half = ql & 1, qt = ql >> 1;  // token half, q-tile
  int bh = (j >> 3) * 8 + xcd;
  int b = bh >> 4, h = bh & 15;
  int q0 = qt * 128;
  int t00 = half * 2048;

  const unsigned short* Qb = Q + (size_t)(b * 512 + q0 + w * 32) * 1024 + h * 64;
  const unsigned short* Kb = Kp + (size_t)(b * 4096) * 1024 + h * 64;
  const unsigned short* Vb = VT + (size_t)(h * 64) * 16384 + b * 4096;
  const float* bzg = bz + (size_t)b * 4096;

  // Q B-operand fragments: 2 strips of 16 q-rows
  bf16x8 bq[2][2];
#pragma unroll
  for (int s = 0; s < 2; ++s)
#pragma unroll
    for (int th = 0; th < 2; ++th)
      bq[s][th] = *(const bf16x8*)(Qb + (size_t)(s * 16 + lh) * 1024 + th * 32 + q4 * 8);

  f32x4 oa[2][4] = {};              // O^T accumulators [strip][d-tile]
  float ls[2] = {0.f, 0.f};

  int rl = lane >> 3, blk = lane & 7;
  int sw = ((blk ^ rl) * 8);        // xor-swizzled 8-ushort block offset in source row

  for (int ti = 0; ti < 32; ++ti) {
    int t = t00 + ti * 64;
    // ---- stage K[64 tok][64 d] and V^T[64 d][64 tok], xor-swizzled blocks ----
#pragma unroll
    for (int r = 0; r < 2; ++r) {
      int seg = r * 4 + w;
      int row = seg * 8 + rl;
      cp16(Kb + (size_t)(t + row) * 1024 + sw, Klds + seg * 512);
      cp16(Vb + (size_t)row * 16384 + t + sw, Vlds + seg * 512);
    }
    __syncthreads();

    // bias (pre-transformed) for this tile's tokens
    float4 bz4[4];
#pragma unroll
    for (int c = 0; c < 4; ++c)
      bz4[c] = *(const float4*)(bzg + t + c * 16 + q4 * 4);

    // K fragments: A[m=tok][k=d], lane m=lh, k=th*32+q4*8..+8
    bf16x8 kf[4][2];
#pragma unroll
    for (int c = 0; c < 4; ++c)
#pragma unroll
      for (int th = 0; th < 2; ++th)
        kf[c][th] = *(const bf16x8*)(Klds + (c * 16 + lh) * 64 + (((th << 2) + q4) ^ (lh & 7)) * 8);
    // V fragments: A[m=d][k=tok], lane m=lh (+c2*16), k=c*16+q4*4..+4
    bf16x4 vf[4][4];
#pragma unroll
    for (int c = 0; c < 4; ++c)
#pragma unroll
      for (int c2 = 0; c2 < 4; ++c2)
        vf[c][c2] = *(const bf16x4*)(Vlds + (c2 * 16 + lh) * 64 +
                                     (((c << 1) + (q4 >> 1)) ^ (lh & 7)) * 8 + (q4 & 1) * 4);

#pragma unroll
    for (int s = 0; s < 2; ++s) {
#pragma unroll
      for (int c = 0; c < 4; ++c) {
        f32x4 z = {};
        z = MFMA32(kf[c][0], bq[s][0], z);
        z = MFMA32(kf[c][1], bq[s][1], z);
        float bzf[4] = {bz4[c].x, bz4[c].y, bz4[c].z, bz4[c].w};
        bf16x4 pb;
        float ps = 0.f;
#pragma unroll
        for (int e = 0; e < 4; ++e) {
          float p = __builtin_amdgcn_exp2f(z[e] + bzf[e]);
          ps += p;
          pb[e] = (short)f2bf(p);
        }
        ls[s] += ps;
#pragma unroll
        for (int c2 = 0; c2 < 4; ++c2)
          oa[s][c2] = MFMA16(vf[c][c2], pb, oa[s][c2]);
      }
    }
    __syncthreads();
  }

  // l: lane holds partial for q=lh; reduce across the 4 q4 groups
#pragma unroll
  for (int s = 0; s < 2; ++s) {
    ls[s] += __shfl_xor(ls[s], 16);
    ls[s] += __shfl_xor(ls[s], 32);
  }

  // partial stores: po[half*256 + bh*4+qt][d=64][q=128]
  int sl = bh * 4 + qt;
  float* pslice = po + (size_t)(half * 256 + sl) * 8192;
#pragma unroll
  for (int s = 0; s < 2; ++s) {
    if (q4 == 0) lp[half * 32768 + sl * 128 + w * 32 + s * 16 + lh] = ls[s];
#pragma unroll
    for (int c2 = 0; c2 < 4; ++c2)
#pragma unroll
      for (int e = 0; e < 4; ++e)
        pslice[(c2 * 16 + q4 * 4 + e) * 128 + w * 32 + s * 16 + lh] = oa[s][c2][e];
  }
}

// ---------- merge token-half partials, normalize, pack to bf16 ao ----------
__global__ void norm_kernel(const float* __restrict__ po, const float* __restrict__ lp,
                            unsigned short* __restrict__ ao) {
  int g = blockIdx.x * 256 + threadIdx.x;   // 262144 threads
  int d8 = (g & 7) * 8;
  int rowid = g >> 3;                        // 0..32767 = bh*512 + qt*128 + qcol
  int bh = rowid >> 9, rq = rowid & 511, qt = rq >> 7, qcol = rq & 127;
  int sl = bh * 4 + qt;
  const float* p0 = po + (size_t)sl * 8192;
  const float* p1 = po + (size_t)(256 + sl) * 8192;
  float l = lp[sl * 128 + qcol] + lp[32768 + sl * 128 + qcol];
  float inv = 1.f / l;
  unsigned short o8[8];
#pragma unroll
  for (int k = 0; k < 8; ++k)
    o8[k] = f2bf((p0[(d8 + k) * 128 + qcol] + p1[(d8 + k) * 128 + qcol]) * inv);
  int b = bh >> 4, h = bh & 15;
  unsigned short* dst = ao + (size_t)(b * 512 + qt * 128 + qcol) * 1024 + h * 64 + d8;
  *(ushort4*)dst = *(ushort4*)o8;
  *(ushort4*)(dst + 4) = *(ushort4*)(o8 + 4);
}

// ---------- launch ----------
extern "C" void kernel_launch(void* const* d_in, const int* in_sizes, int n_in,
                              void* d_out, int out_size, void* d_ws, size_t ws_size,
                              hipStream_t stream) {
  const float* query  = (const float*)d_in[0];
  const float* memory = (const float*)d_in[1];
  const float* bias   = (const float*)d_in[2];
  const float* Wq     = (const float*)d_in[3];
  const float* Wk     = (const float*)d_in[4];
  const float* Wv     = (const float*)d_in[5];
  const float* Wo     = (const float*)d_in[6];
  float* out = (float*)d_out;

  unsigned short* ws  = (unsigned short*)d_ws;
  unsigned short* qbf = ws;                       // 2048*1024
  unsigned short* mbf = qbf + 2097152;            // 16384*1024
  unsigned short* WqT = mbf + 16777216;           // 4 x 1024*1024 contiguous
  unsigned short* WkT = WqT + 1048576;
  unsigned short* WvT = WkT + 1048576;
  unsigned short* WoT = WvT + 1048576;
  unsigned short* qp  = WoT + 1048576;            // 2048*1024 (scaled q proj)
  unsigned short* kp  = qp + 2097152;             // 16384*1024
  unsigned short* vT  = kp + 16777216;            // 1024*16384
  unsigned short* ao  = vT + 16777216;            // 2048*1024
  float* bzw = (float*)(ao + 2097152);            // 16384 floats (bias*log2e-16)
  // po/lp alias qbf+mbf (dead after the projection GEMMs)
  float* po = (float*)ws;                         // 512 slices x 8192 floats = 16 MB
  float* lp = po + 4194304;                       // 65536 floats

  conv_both<<<18448, 256, 0, stream>>>(query, memory, bias, qbf, mbf, bzw);
  transpose4<<<dim3(32, 32, 4), dim3(32, 8), 0, stream>>>(Wq, Wk, Wv, Wo, WqT);

  // q = (query@Wq) * (1/8)*log2e   [2048 x 1024]
  gemm_bt64<<<dim3(16, 16), 256, 0, stream>>>(qbf, WqT, nullptr, qp, 2048, 1024, 1024, 0.125f * LOG2E);
  // fused: kp = memory@Wk, vT = (memory@Wv)^T  — B-from-L2, A quad-buffer
  gemm_kv<<<512, 512, 0, stream>>>(mbf, WkT, WvT, kp, vT);

  attn_kernel<<<512, 256, 0, stream>>>(qp, kp, vT, bzw, po, lp);
  norm_kernel<<<1024, 256, 0, stream>>>(po, lp, ao);

  // out = ao @ Wo (fp32 out)
  gemm_bt64<<<dim3(16, 16), 256, 0, stream>>>(ao, WoT, out, nullptr, 2048, 1024, 1024, 1.f);
}

// Round 8
// 290.471 us; speedup vs baseline: 1.2503x; 1.2503x over previous
//
#include <hip/hip_runtime.h>

// ---------- types ----------
typedef __attribute__((ext_vector_type(8))) short bf16x8;   // 8 bf16 in 4 VGPRs
typedef __attribute__((ext_vector_type(4))) short bf16x4;   // 4 bf16 in 2 VGPRs
typedef __attribute__((ext_vector_type(4))) float f32x4;    // MFMA C/D

#define MFMA32(a,b,c) __builtin_amdgcn_mfma_f32_16x16x32_bf16((a),(b),(c),0,0,0)
#define MFMA16(a,b,c) __builtin_amdgcn_mfma_f32_16x16x16bf16_1k((a),(b),(c),0,0,0)
#define LOG2E 1.44269504f

__device__ __forceinline__ unsigned short f2bf(float f) {
  unsigned int u = __float_as_uint(f);
  u += 0x7fffu + ((u >> 16) & 1u);      // round-to-nearest-even
  return (unsigned short)(u >> 16);
}

// async global->LDS, 16B per lane; LDS dest = wave-uniform base + lane*16
__device__ __forceinline__ void cp16(const void* g, void* l) {
  __builtin_amdgcn_global_load_lds((const __attribute__((address_space(1))) void*)g,
                                   (__attribute__((address_space(3))) void*)l, 16, 0, 0);
}

// ---------- fp32 -> bf16 (query, memory) + bias pre-transform, one launch ----
__global__ void conv_both(const float* __restrict__ q, const float* __restrict__ m,
                          const float* __restrict__ bias,
                          unsigned short* __restrict__ qo, unsigned short* __restrict__ mo,
                          float* __restrict__ bz) {
  int i = blockIdx.x * 256 + threadIdx.x;   // grid covers 4718592 + 4096 float4s
  if (i < 524288) {
    float4 v = ((const float4*)q)[i];
    ushort4 o; o.x = f2bf(v.x); o.y = f2bf(v.y); o.z = f2bf(v.z); o.w = f2bf(v.w);
    ((ushort4*)qo)[i] = o;
  } else if (i < 4718592) {
    int j = i - 524288;
    float4 v = ((const float4*)m)[j];
    ushort4 o; o.x = f2bf(v.x); o.y = f2bf(v.y); o.z = f2bf(v.z); o.w = f2bf(v.w);
    ((ushort4*)mo)[j] = o;
  } else {
    int j = i - 4718592;                   // < 4096: bias -> bias*log2e - 16
    float4 v = ((const float4*)bias)[j];
    float4 o;
    o.x = __builtin_fmaf(v.x, LOG2E, -16.f);
    o.y = __builtin_fmaf(v.y, LOG2E, -16.f);
    o.z = __builtin_fmaf(v.z, LOG2E, -16.f);
    o.w = __builtin_fmaf(v.w, LOG2E, -16.f);
    ((float4*)bz)[j] = o;
  }
}

// ---------- 1024x1024 transpose+convert for all 4 weights in one launch ----------
__global__ void transpose4(const float* __restrict__ Wq, const float* __restrict__ Wk,
                           const float* __restrict__ Wv, const float* __restrict__ Wo,
                           unsigned short* __restrict__ dst) {
  __shared__ float t[32][33];
  int z = blockIdx.z;
  const float* W = (z == 0) ? Wq : (z == 1) ? Wk : (z == 2) ? Wv : Wo;
  unsigned short* WT = dst + (size_t)z * 1048576;
  int bx = blockIdx.x * 32, by = blockIdx.y * 32;
  int x = threadIdx.x, y0 = threadIdx.y;
#pragma unroll
  for (int r = 0; r < 4; ++r)
    t[y0 + r * 8][x] = W[(size_t)(by + y0 + r * 8) * 1024 + bx + x];
  __syncthreads();
#pragma unroll
  for (int r = 0; r < 4; ++r)
    WT[(size_t)(bx + y0 + r * 8) * 1024 + by + x] = f2bf(t[x][y0 + r * 8]);
}

// ---------- fused K/V projection — r13: 2 blocks/CU cross-block overlap -----
// r12 refuted (B-from-global: vmcnt FIFO mixing B loads with cp16 prefetch
// drained the pipeline every half-tile -> 17% MfmaUtil). r11 analysis: the
// 1-block/CU 8-wave barrier-locked structure serializes LDS<->MFMA (all waves
// in phase). Fix = m114/m97 mechanism: BM=128, BN=64, BK=64, 256 thr (4 waves
// 2Mx2N), dbuf 2x32KB=64KB -> TWO resident blocks/CU. Desynced blocks overlap
// naturally: one block's MFMA covers the other's stage/ds_read/barrier.
// Same single-sync-per-tile protocol as r11 (vmcnt0+lgkmcnt0+s_barrier at
// tile top; stage t+1 -> other buffer; 16 frag reads; 32 MFMA). Same 8-slot
// T2 swizzle (rows stay 64 ushorts = 128B). Strip-major XCD swizzle: 16
// consecutive blocks share one A strip (L2-resident).
__global__ __launch_bounds__(256, 2) void gemm_kv(
    const unsigned short* __restrict__ A,   // mbf [16384][1024]
    const unsigned short* __restrict__ Bk,  // WkT [1024][1024]
    const unsigned short* __restrict__ Bv,  // WvT [1024][1024]
    unsigned short* __restrict__ Kp,        // [16384][1024]
    unsigned short* __restrict__ Vt)        // [1024][16384]
{
  // buf b at b*16384 ushorts: A[128][64]@0, Bk[64][64]@8192, Bv[64][64]@12288
  __shared__ __attribute__((aligned(16))) unsigned short lds[32768]; // 64 KB
  const int tid = threadIdx.x;
  const int w = tid >> 6, lane = tid & 63;
  const int lh = lane & 15, q4 = lane >> 4;
  const int id = blockIdx.x;
  const int xcd = id & 7, j = id >> 3;            // 256 blocks per XCD
  const int tm = (xcd * 16 + (j >> 4)) * 128;     // 16 m-strips per XCD
  const int tn = (j & 15) * 64;                   // n cycles inner
  const int wm = (w >> 1) * 64, wn = (w & 1) * 32;

  // staging lane geometry (source-side T2 swizzle, 64B segments stay whole)
  const int r8 = lane >> 3;                       // row within 8-row chunk
  const int scol = ((lane & 7) ^ r8) * 8;         // swizzled source k-slot
  const int srow = w * 8 + r8;                    // row within 32-row pass
  // fragment-read swizzled slot offsets (row&7 == lh&7 for all frag rows)
  const int fs0 = ((0 + q4) ^ (lh & 7)) * 8;
  const int fs1 = ((4 + q4) ^ (lh & 7)) * 8;

  const unsigned short* Ag = A  + (size_t)tm * 1024 + scol;
  const unsigned short* Kg = Bk + (size_t)tn * 1024 + scol;
  const unsigned short* Vg = Bv + (size_t)tn * 1024 + scol;

#define STG(BUF,KT) do {                                                      \
    cp16(Ag + (size_t)( 0 + srow) * 1024 + (KT)*64, lds + (BUF)*16384 +         w*512); \
    cp16(Ag + (size_t)(32 + srow) * 1024 + (KT)*64, lds + (BUF)*16384 +  2048 + w*512); \
    cp16(Ag + (size_t)(64 + srow) * 1024 + (KT)*64, lds + (BUF)*16384 +  4096 + w*512); \
    cp16(Ag + (size_t)(96 + srow) * 1024 + (KT)*64, lds + (BUF)*16384 +  6144 + w*512); \
    cp16(Kg + (size_t)( 0 + srow) * 1024 + (KT)*64, lds + (BUF)*16384 +  8192 + w*512); \
    cp16(Kg + (size_t)(32 + srow) * 1024 + (KT)*64, lds + (BUF)*16384 + 10240 + w*512); \
    cp16(Vg + (size_t)( 0 + srow) * 1024 + (KT)*64, lds + (BUF)*16384 + 12288 + w*512); \
    cp16(Vg + (size_t)(32 + srow) * 1024 + (KT)*64, lds + (BUF)*16384 + 14336 + w*512); \
  } while (0)

  f32x4 acck[4][2] = {}, accv[4][2] = {};

  // ---- prologue: stage tile 0 into buf 0 (drained by first __syncthreads)
  STG(0, 0);

  for (int t = 0; t < 16; ++t) {
    const unsigned short* bse = lds + (t & 1) * 16384;
    __syncthreads();                 // vmcnt(0)+lgkmcnt(0)+s_barrier
    if (t < 15) STG((t & 1) ^ 1, t + 1);
    // kh = 0
    {
      bf16x8 a0[4], bk0[2], bv0[2];
#pragma unroll
      for (int m = 0; m < 4; ++m)
        a0[m] = *(const bf16x8*)(bse + (wm + m * 16 + lh) * 64 + fs0);
#pragma unroll
      for (int n = 0; n < 2; ++n) {
        bk0[n] = *(const bf16x8*)(bse +  8192 + (wn + n * 16 + lh) * 64 + fs0);
        bv0[n] = *(const bf16x8*)(bse + 12288 + (wn + n * 16 + lh) * 64 + fs0);
      }
      __builtin_amdgcn_s_setprio(1);
#pragma unroll
      for (int m = 0; m < 4; ++m)
#pragma unroll
        for (int n = 0; n < 2; ++n) {
          acck[m][n] = MFMA32(a0[m], bk0[n], acck[m][n]);
          accv[m][n] = MFMA32(a0[m], bv0[n], accv[m][n]);
        }
      __builtin_amdgcn_s_setprio(0);
    }
    // kh = 1
    {
      bf16x8 a1[4], bk1[2], bv1[2];
#pragma unroll
      for (int m = 0; m < 4; ++m)
        a1[m] = *(const bf16x8*)(bse + (wm + m * 16 + lh) * 64 + fs1);
#pragma unroll
      for (int n = 0; n < 2; ++n) {
        bk1[n] = *(const bf16x8*)(bse +  8192 + (wn + n * 16 + lh) * 64 + fs1);
        bv1[n] = *(const bf16x8*)(bse + 12288 + (wn + n * 16 + lh) * 64 + fs1);
      }
      __builtin_amdgcn_s_setprio(1);
#pragma unroll
      for (int m = 0; m < 4; ++m)
#pragma unroll
        for (int n = 0; n < 2; ++n) {
          acck[m][n] = MFMA32(a1[m], bk1[n], acck[m][n]);
          accv[m][n] = MFMA32(a1[m], bv1[n], accv[m][n]);
        }
      __builtin_amdgcn_s_setprio(0);
    }
  }
#undef STG

  // Kp epilogue: row-major 2B stores coalesce within lh groups (r4-verified)
#pragma unroll
  for (int m = 0; m < 4; ++m)
#pragma unroll
    for (int n = 0; n < 2; ++n) {
      int row = tm + wm + m * 16 + q4 * 4;
      int col = tn + wn + n * 16 + lh;
#pragma unroll
      for (int e = 0; e < 4; ++e)
        Kp[(size_t)(row + e) * 1024 + col] = f2bf(acck[m][n][e]);
    }

  // Vt epilogue via LDS: write C-layout (xor-swizzled [64 col][128 row] tile,
  // r5-verified pattern), read back coalesced.
  __syncthreads();
#pragma unroll
  for (int m = 0; m < 4; ++m)
#pragma unroll
    for (int n = 0; n < 2; ++n) {
      int row = wm + m * 16 + q4 * 4;       // block-local token (+e consecutive)
      int col = wn + n * 16 + lh;           // block-local d (0..63)
      ushort4 v4;
      v4.x = f2bf(accv[m][n][0]); v4.y = f2bf(accv[m][n][1]);
      v4.z = f2bf(accv[m][n][2]); v4.w = f2bf(accv[m][n][3]);
      *(ushort4*)(lds + col * 128 + (row ^ ((col & 15) << 3))) = v4;
    }
  __syncthreads();
#pragma unroll
  for (int p = 0; p < 4; ++p) {
    int col = p * 16 + (tid >> 4);                  // 0..63
    int jb = tid & 15;                              // 8-row block in 128 rows
    const unsigned short* src = lds + col * 128 + ((jb ^ (col & 15)) << 3);
    *(int4*)(Vt + (size_t)(tn + col) * 16384 + tm + jb * 8) = *(const int4*)src;
  }
}

// ---------- bf16 GEMM 128x64 tile (q-proj, out-proj) ----------
// r12 quad-buffer window (sync per 2 k-steps); r6 T2 swizzle.
__global__ __launch_bounds__(256) void gemm_bt64(
    const unsigned short* __restrict__ A, const unsigned short* __restrict__ B,
    float* __restrict__ Cf, unsigned short* __restrict__ Cb,
    int M, int N, int K, float scale)
{
  // buffer b at b*6144 ushorts: A[128][32]@0, B[64][32]@4096
  __shared__ __attribute__((aligned(16))) unsigned short lds[24576]; // 48 KB
  int w = threadIdx.x >> 6, lane = threadIdx.x & 63;
  int lh = lane & 15, q4 = lane >> 4;
  int tm = blockIdx.y * 128, tn = blockIdx.x * 64;
  int wm = (w & 1) * 64, wn = (w >> 1) * 32;

  int srow = lane >> 2;
  int scol = ((lane & 3) ^ ((lane >> 3) & 3)) << 3;
  int q4s = (q4 ^ ((lh >> 1) & 3)) << 3;

#define STG64(BUF,K0)                                                          \
  {                                                                            \
    _Pragma("unroll") for (int i = 0; i < 2; ++i) {                            \
      int c = w * 2 + i;                                                       \
      cp16(A + (size_t)(tm + c * 16 + srow) * K + (K0) + scol,                 \
           lds + (BUF) * 6144 + c * 512);                                      \
    }                                                                          \
    cp16(B + (size_t)(tn + w * 16 + srow) * K + (K0) + scol,                   \
         lds + (BUF) * 6144 + 4096 + w * 512);                                 \
  }

  f32x4 acc[4][2] = {};
  const int nw = K >> 6;               // windows of 2 k-steps

  STG64(0, 0);
  STG64(1, 32);

  for (int s = 0; s < nw; ++s) {
    __syncthreads();                   // vmcnt(0)+lgkmcnt(0)+s_barrier
    if (s + 1 < nw) {
      STG64((2 * s + 2) & 3, (2 * s + 2) << 5);
      STG64((2 * s + 3) & 3, (2 * s + 3) << 5);
    }
#pragma unroll
    for (int u = 0; u < 2; ++u) {
      const unsigned short* bse = lds + ((2 * s + u) & 3) * 6144;
      bf16x8 afr[4], bfr[2];
#pragma unroll
      for (int r = 0; r < 4; ++r)
        afr[r] = *(const bf16x8*)(bse + (wm + r * 16 + lh) * 32 + q4s);
#pragma unroll
      for (int c = 0; c < 2; ++c)
        bfr[c] = *(const bf16x8*)(bse + 4096 + (wn + c * 16 + lh) * 32 + q4s);
      __builtin_amdgcn_s_setprio(1);
#pragma unroll
      for (int r = 0; r < 4; ++r)
#pragma unroll
        for (int c = 0; c < 2; ++c)
          acc[r][c] = MFMA32(afr[r], bfr[c], acc[r][c]);
      __builtin_amdgcn_s_setprio(0);
    }
  }
#undef STG64

#pragma unroll
  for (int r = 0; r < 4; ++r)
#pragma unroll
    for (int c = 0; c < 2; ++c)
#pragma unroll
      for (int e = 0; e < 4; ++e) {
        int row = tm + wm + r * 16 + q4 * 4 + e;
        int col = tn + wn + c * 16 + lh;
        if (Cb) Cb[(size_t)row * N + col] = f2bf(acc[r][c][e] * scale);
        else    Cf[(size_t)row * N + col] = acc[r][c][e] * scale;
      }
}

// ---------- attention — r13: single-sync double-buffered K/V staging --------
// Was: {8 cp16 -> __syncthreads (drains stages serially) -> compute ->
// __syncthreads} per tile. Now: K/V LDS doubled (8KB each); per tile ONE
// __syncthreads at top, then stage(ti+1 -> buf^1) flies under compute(ti).
// Hazard proof identical to gemm_kv r11: sync's lgkmcnt(0) drains reads of
// the buffer being restaged next tile; vmcnt(0) drains the stages before
// their first read.
__global__ __launch_bounds__(256) void attn_kernel(
    const unsigned short* __restrict__ Q, const unsigned short* __restrict__ Kp,
    const unsigned short* __restrict__ VT, const float* __restrict__ bz,
    float* __restrict__ po, float* __restrict__ lp)
{
  __shared__ __attribute__((aligned(16))) unsigned short Klds[8192]; // 2 bufs
  __shared__ __attribute__((aligned(16))) unsigned short Vlds[8192]; // 2 bufs
  int w = threadIdx.x >> 6, lane = threadIdx.x & 63;
  int lh = lane & 15, q4 = lane >> 4;

  // XCD swizzle: same-bh blocks land on same XCD (bh & 7 == xcd)
  int id = blockIdx.x;
  int xcd = id & 7, j = id >> 3;
  int ql = j & 7;                   // 8 blocks per bh
  int half = ql & 1, qt = ql >> 1;  // token half, q-tile
  int bh = (j >> 3) * 8 + xcd;
  int b = bh >> 4, h = bh & 15;
  int q0 = qt * 128;
  int t00 = half * 2048;

  const unsigned short* Qb = Q + (size_t)(b * 512 + q0 + w * 32) * 1024 + h * 64;
  const unsigned short* Kb = Kp + (size_t)(b * 4096) * 1024 + h * 64;
  const unsigned short* Vb = VT + (size_t)(h * 64) * 16384 + b * 4096;
  const float* bzg = bz + (size_t)b * 4096;

  // Q B-operand fragments: 2 strips of 16 q-rows
  bf16x8 bq[2][2];
#pragma unroll
  for (int s = 0; s < 2; ++s)
#pragma unroll
    for (int th = 0; th < 2; ++th)
      bq[s][th] = *(const bf16x8*)(Qb + (size_t)(s * 16 + lh) * 1024 + th * 32 + q4 * 8);

  f32x4 oa[2][4] = {};              // O^T accumulators [strip][d-tile]
  float ls[2] = {0.f, 0.f};

  int rl = lane >> 3, blk = lane & 7;
  int sw = ((blk ^ rl) * 8);        // xor-swizzled 8-ushort block offset in source row

  // prologue: stage tile 0 into buf 0
  {
    int t = t00;
#pragma unroll
    for (int r = 0; r < 2; ++r) {
      int seg = r * 4 + w;
      int row = seg * 8 + rl;
      cp16(Kb + (size_t)(t + row) * 1024 + sw, Klds + seg * 512);
      cp16(Vb + (size_t)row * 16384 + t + sw, Vlds + seg * 512);
    }
  }

  for (int ti = 0; ti < 32; ++ti) {
    int t = t00 + ti * 64;
    __syncthreads();                 // vmcnt(0)+lgkmcnt(0)+s_barrier
    if (ti < 31) {
      int t2 = t + 64;
      int bo2 = ((ti + 1) & 1) * 4096;
#pragma unroll
      for (int r = 0; r < 2; ++r) {
        int seg = r * 4 + w;
        int row = seg * 8 + rl;
        cp16(Kb + (size_t)(t2 + row) * 1024 + sw, Klds + bo2 + seg * 512);
        cp16(Vb + (size_t)row * 16384 + t2 + sw, Vlds + bo2 + seg * 512);
      }
    }
    const unsigned short* Kl = Klds + (ti & 1) * 4096;
    const unsigned short* Vl = Vlds + (ti & 1) * 4096;

    // bias (pre-transformed) for this tile's tokens
    float4 bz4[4];
#pragma unroll
    for (int c = 0; c < 4; ++c)
      bz4[c] = *(const float4*)(bzg + t + c * 16 + q4 * 4);

    // K fragments: A[m=tok][k=d], lane m=lh, k=th*32+q4*8..+8
    bf16x8 kf[4][2];
#pragma unroll
    for (int c = 0; c < 4; ++c)
#pragma unroll
      for (int th = 0; th < 2; ++th)
        kf[c][th] = *(const bf16x8*)(Kl + (c * 16 + lh) * 64 + (((th << 2) + q4) ^ (lh & 7)) * 8);
    // V fragments: A[m=d][k=tok], lane m=lh (+c2*16), k=c*16+q4*4..+4
    bf16x4 vf[4][4];
#pragma unroll
    for (int c = 0; c < 4; ++c)
#pragma unroll
      for (int c2 = 0; c2 < 4; ++c2)
        vf[c][c2] = *(const bf16x4*)(Vl + (c2 * 16 + lh) * 64 +
                                     (((c << 1) + (q4 >> 1)) ^ (lh & 7)) * 8 + (q4 & 1) * 4);

#pragma unroll
    for (int s = 0; s < 2; ++s) {
#pragma unroll
      for (int c = 0; c < 4; ++c) {
        f32x4 z = {};
        z = MFMA32(kf[c][0], bq[s][0], z);
        z = MFMA32(kf[c][1], bq[s][1], z);
        float bzf[4] = {bz4[c].x, bz4[c].y, bz4[c].z, bz4[c].w};
        bf16x4 pb;
        float ps = 0.f;
#pragma unroll
        for (int e = 0; e < 4; ++e) {
          float p = __builtin_amdgcn_exp2f(z[e] + bzf[e]);
          ps += p;
          pb[e] = (short)f2bf(p);
        }
        ls[s] += ps;
#pragma unroll
        for (int c2 = 0; c2 < 4; ++c2)
          oa[s][c2] = MFMA16(vf[c][c2], pb, oa[s][c2]);
      }
    }
  }

  // l: lane holds partial for q=lh; reduce across the 4 q4 groups
#pragma unroll
  for (int s = 0; s < 2; ++s) {
    ls[s] += __shfl_xor(ls[s], 16);
    ls[s] += __shfl_xor(ls[s], 32);
  }

  // partial stores: po[half*256 + bh*4+qt][d=64][q=128]
  int sl = bh * 4 + qt;
  float* pslice = po + (size_t)(half * 256 + sl) * 8192;
#pragma unroll
  for (int s = 0; s < 2; ++s) {
    if (q4 == 0) lp[half * 32768 + sl * 128 + w * 32 + s * 16 + lh] = ls[s];
#pragma unroll
    for (int c2 = 0; c2 < 4; ++c2)
#pragma unroll
      for (int e = 0; e < 4; ++e)
        pslice[(c2 * 16 + q4 * 4 + e) * 128 + w * 32 + s * 16 + lh] = oa[s][c2][e];
  }
}

// ---------- merge token-half partials, normalize, pack to bf16 ao ----------
__global__ void norm_kernel(const float* __restrict__ po, const float* __restrict__ lp,
                            unsigned short* __restrict__ ao) {
  int g = blockIdx.x * 256 + threadIdx.x;   // 262144 threads
  int d8 = (g & 7) * 8;
  int rowid = g >> 3;                        // 0..32767 = bh*512 + qt*128 + qcol
  int bh = rowid >> 9, rq = rowid & 511, qt = rq >> 7, qcol = rq & 127;
  int sl = bh * 4 + qt;
  const float* p0 = po + (size_t)sl * 8192;
  const float* p1 = po + (size_t)(256 + sl) * 8192;
  float l = lp[sl * 128 + qcol] + lp[32768 + sl * 128 + qcol];
  float inv = 1.f / l;
  unsigned short o8[8];
#pragma unroll
  for (int k = 0; k < 8; ++k)
    o8[k] = f2bf((p0[(d8 + k) * 128 + qcol] + p1[(d8 + k) * 128 + qcol]) * inv);
  int b = bh >> 4, h = bh & 15;
  unsigned short* dst = ao + (size_t)(b * 512 + qt * 128 + qcol) * 1024 + h * 64 + d8;
  *(ushort4*)dst = *(ushort4*)o8;
  *(ushort4*)(dst + 4) = *(ushort4*)(o8 + 4);
}

// ---------- launch ----------
extern "C" void kernel_launch(void* const* d_in, const int* in_sizes, int n_in,
                              void* d_out, int out_size, void* d_ws, size_t ws_size,
                              hipStream_t stream) {
  const float* query  = (const float*)d_in[0];
  const float* memory = (const float*)d_in[1];
  const float* bias   = (const float*)d_in[2];
  const float* Wq     = (const float*)d_in[3];
  const float* Wk     = (const float*)d_in[4];
  const float* Wv     = (const float*)d_in[5];
  const float* Wo     = (const float*)d_in[6];
  float* out = (float*)d_out;

  unsigned short* ws  = (unsigned short*)d_ws;
  unsigned short* qbf = ws;                       // 2048*1024
  unsigned short* mbf = qbf + 2097152;            // 16384*1024
  unsigned short* WqT = mbf + 16777216;           // 4 x 1024*1024 contiguous
  unsigned short* WkT = WqT + 1048576;
  unsigned short* WvT = WkT + 1048576;
  unsigned short* WoT = WvT + 1048576;
  unsigned short* qp  = WoT + 1048576;            // 2048*1024 (scaled q proj)
  unsigned short* kp  = qp + 2097152;             // 16384*1024
  unsigned short* vT  = kp + 16777216;            // 1024*16384
  unsigned short* ao  = vT + 16777216;            // 2048*1024
  float* bzw = (float*)(ao + 2097152);            // 16384 floats (bias*log2e-16)
  // po/lp alias qbf+mbf (dead after the projection GEMMs)
  float* po = (float*)ws;                         // 512 slices x 8192 floats = 16 MB
  float* lp = po + 4194304;                       // 65536 floats

  conv_both<<<18448, 256, 0, stream>>>(query, memory, bias, qbf, mbf, bzw);
  transpose4<<<dim3(32, 32, 4), dim3(32, 8), 0, stream>>>(Wq, Wk, Wv, Wo, WqT);

  // q = (query@Wq) * (1/8)*log2e   [2048 x 1024]
  gemm_bt64<<<dim3(16, 16), 256, 0, stream>>>(qbf, WqT, nullptr, qp, 2048, 1024, 1024, 0.125f * LOG2E);
  // fused: kp = memory@Wk, vT = (memory@Wv)^T — 128x64 tiles, 2 blocks/CU
  gemm_kv<<<2048, 256, 0, stream>>>(mbf, WkT, WvT, kp, vT);

  attn_kernel<<<512, 256, 0, stream>>>(qp, kp, vT, bzw, po, lp);
  norm_kernel<<<1024, 256, 0, stream>>>(po, lp, ao);

  // out = ao @ Wo (fp32 out)
  gemm_bt64<<<dim3(16, 16), 256, 0, stream>>>(ao, WoT, out, nullptr, 2048, 1024, 1024, 1.f);
}